// Round 8
// baseline (26.031 us; speedup 1.0000x reference)
//
#include <hip/hip_runtime.h>

#define BB 128
#define TT 512
#define NBLK 1024        // 128 rows x 8 lag-chunks
#define LAG_PENALTY 0.5f

// Single-node fused kernel. Per-block partial -> device-scope store ->
// counter ticket; the last block to finish (old % NBLK == NBLK-1: exactly one
// winner per call for ANY initial counter value, since the 1024 returned
// tickets form a complete residue system mod 1024 -> poison/replay safe)
// re-reads partials via atomic RMW (coherence-point reads, XCD-stale-proof)
// and writes out[0]. No spin, no reset, bit-identical result per call.

__global__ __launch_bounds__(512, 4) void WeightedLagDenseLoss_fused(
    const float* __restrict__ pred,
    const float* __restrict__ tgt,
    const float* __restrict__ wts,
    float* __restrict__ part,            // d_ws: NBLK floats
    unsigned int* __restrict__ counter,  // d_ws + NBLK floats
    float* __restrict__ out)
{
    __shared__ float4 s_ext4[256];   // 1024 floats: row [0..511], g511-pad
    __shared__ float  s_part[8];
    __shared__ unsigned int s_old;
    float* s_ext = reinterpret_cast<float*>(s_ext4);

    const int bid = blockIdx.x;
    const int row = bid >> 3;        // 0..127
    const int s   = bid & 7;         // lag chunk: lags [64s, 64s+64)
    const int tid = threadIdx.x;
    const int j   = tid & 127;       // t-group: t = 4j..4j+3
    const int q   = tid >> 7;        // lag subchunk: lags [64s+16q, +16)

    // Stage extended target row (clamp-pad with g[511])
    const float g511 = tgt[row * TT + TT - 1];
    s_ext[tid]       = tgt[row * TT + tid];
    s_ext[TT + tid]  = g511;
    __syncthreads();

    // 1/l for this thread's 16 lags, via v_rcp (off the LDS pipe)
    const int L0 = 64 * s + 16 * q;
    float r[16];
    #pragma unroll
    for (int i = 0; i < 16; ++i) {
        const int l = L0 + i;
        r[i] = (l == 0) ? 0.0f : __builtin_amdgcn_rcpf((float)l);
    }

    const float4 p = *reinterpret_cast<const float4*>(&pred[row * TT + 4 * j]);

    // 20-float sliding window: 5 aligned ds_read_b128
    const int base4 = j + (L0 >> 2);
    float4 w4[5];
    #pragma unroll
    for (int k = 0; k < 5; ++k) w4[k] = s_ext4[base4 + k];
    const float* w = reinterpret_cast<const float*>(w4);

    float acc = 0.0f;     // sum over 16 lags x 4 t of (1/l) * d^2
    float mse = 0.0f;     // plain MSE tile (l=0 group), added once
    const bool own_mse = (s == 0) && (q == 0);

    #pragma unroll
    for (int k = 0; k < 4; ++k) {
        #pragma unroll
        for (int bb = 0; bb < 4; ++bb) {
            const int o = 4 * k + bb;
            const float d0 = p.x - w[o + 0];
            const float d1 = p.y - w[o + 1];
            const float d2 = p.z - w[o + 2];
            const float d3 = p.w - w[o + 3];
            const float sb = d0 * d0 + d1 * d1 + d2 * d2 + d3 * d3;
            acc = fmaf(r[o], sb, acc);
            if (k == 0 && bb == 0 && own_mse) mse = sb;
        }
    }

    float v = fmaf(LAG_PENALTY, acc, mse) * wts[row] * (1.0f / (float)(BB * TT));

    // block-local reduction
    for (int off = 32; off > 0; off >>= 1)
        v += __shfl_down(v, off, 64);
    if ((tid & 63) == 0) s_part[tid >> 6] = v;
    __syncthreads();

    if (tid == 0) {
        float sum = 0.0f;
        #pragma unroll
        for (int i = 0; i < 8; ++i) sum += s_part[i];
        atomicExch(&part[bid], sum);   // device-scope publish of the partial
        __threadfence();               // release before taking the ticket
        s_old = atomicAdd(counter, 1u);
    }
    __syncthreads();

    // Last-finishing block reduces all partials
    if ((s_old & (NBLK - 1)) == (NBLK - 1)) {
        __threadfence();               // acquire
        float rsum = atomicAdd(&part[tid], 0.0f)
                   + atomicAdd(&part[tid + 512], 0.0f);  // coherence-point reads
        for (int off = 32; off > 0; off >>= 1)
            rsum += __shfl_down(rsum, off, 64);
        if ((tid & 63) == 0) s_part[tid >> 6] = rsum;
        __syncthreads();
        if (tid == 0) {
            float total = 0.0f;
            #pragma unroll
            for (int i = 0; i < 8; ++i) total += s_part[i];
            out[0] = total;            // overwrite, no zero-init needed
        }
    }
}

extern "C" void kernel_launch(void* const* d_in, const int* in_sizes, int n_in,
                              void* d_out, int out_size, void* d_ws, size_t ws_size,
                              hipStream_t stream) {
    const float* pred = (const float*)d_in[0];
    const float* tgt  = (const float*)d_in[1];
    const float* wts  = (const float*)d_in[2];
    float* out  = (float*)d_out;
    float* part = (float*)d_ws;                        // NBLK floats
    unsigned int* counter = (unsigned int*)((float*)d_ws + NBLK);

    WeightedLagDenseLoss_fused<<<dim3(NBLK), dim3(TT), 0, stream>>>(
        pred, tgt, wts, part, counter, out);
}